// Round 6
// baseline (539.386 us; speedup 1.0000x reference)
//
#include <hip/hip_runtime.h>
#include <hip/hip_cooperative_groups.h>
#include <math.h>
namespace cg = cooperative_groups;

// ---- static config (mirror of reference) ----
#define GNUM 4
#define NG 512
#define NN 2048
#define EE 32768
#define HC 128
#define HEADS 4
#define HID 32
#define GRID_PTS 500
#define QN 20
#define ODIM 32
#define MAXE 160              // per-dst edge cap (deg ~ Poisson(16); P(>159) ~ 0)
#define NBLK 512

#define LOG2E 1.44269504088896340736f
#define NEG_HALF_LOG2E -0.72134752044448170368f
#define N_POW_M02 0.2871745887492588f   // 512^-0.2
#define SIG_K 144.269504089f            // 100 * log2(e)

__device__ __forceinline__ float fexp2(float x){ return __builtin_amdgcn_exp2f(x); }
__device__ __forceinline__ float frcp(float x){ return __builtin_amdgcn_rcpf(x); }

struct SmemKDE {
  __align__(16) float2 xs[NG];   // (x, x^2) 4KB
  float4 wred4[8];
  float sc[4];
  float wsum[8], woff[9];
  float redw[QN][8], redg[QN][8];
  float qs[QN];
};
struct SmemXW  { float rows[4][HC]; };
struct SmemGat {
  int   ssrc[4][MAXE];
  float sexp[4][MAXE][HEADS];
  float smax[4][HEADS], sfac[4][HEADS];
};
union Smem { SmemKDE kde; SmemXW xw; SmemGat gat; };

struct Params {
  const float *x;
  const int *src, *dst;
  const float *W[2], *As[2], *Ad[2], *Bi[2];
  const float *lpW[3], *lpb[3], *kW[3], *kb[3];
  const float *poolw, *beta, *h0;
  float *out;
  float *cur1, *cur2, *xh, *als, *ald, *macc, *kacc;
  int *pos, *csr;
};

// ---------------- KDE readout phase (one (g,d) per block) ----------------
__device__ void kde_phase(Smem& sm, const float* __restrict__ cur, int do_relu,
        const float* __restrict__ kW, const float* __restrict__ kb, float* __restrict__ kacc,
        const float* __restrict__ lpW, const float* __restrict__ lpb,
        const float* __restrict__ poolw, float* __restrict__ macc){
  int b = blockIdx.x;
  int g = b >> 7, d = b & 127;
  int t = threadIdx.x;
  int lane = t & 63, wave = t >> 6;
  float v = cur[((size_t)g*NG + t)*HC + d];
  if (do_relu) v = fmaxf(v, 0.f);
  sm.kde.xs[t] = make_float2(v, v*v);
  float mn=v, mx=v, smv=v, sq=v*v;
  #pragma unroll
  for (int m=32; m>0; m>>=1){
    mn = fminf(mn, __shfl_xor(mn, m, 64));
    mx = fmaxf(mx, __shfl_xor(mx, m, 64));
    smv += __shfl_xor(smv, m, 64);
    sq += __shfl_xor(sq, m, 64);
  }
  if (lane==0) sm.kde.wred4[wave] = make_float4(mn,mx,smv,sq);
  __syncthreads();
  if (t==0){
    float4 r = sm.kde.wred4[0];
    #pragma unroll
    for (int i=1;i<8;++i){
      float4 bb = sm.kde.wred4[i];
      r.x = fminf(r.x,bb.x); r.y = fmaxf(r.y,bb.y); r.z += bb.z; r.w += bb.w;
    }
    float mean = r.z * (1.f/NG);
    float var  = fmaxf(r.w*(1.f/NG) - mean*mean, 0.f);
    float sd   = sqrtf(var) + (1e-8f/3.f);
    float h    = 1.06f * sd * N_POW_M02;
    float lo = r.x - 1e-6f, hi = r.y + 1e-6f;
    sm.kde.sc[0] = lo;
    sm.kde.sc[1] = (hi-lo)*(1.f/(GRID_PTS-1));
    sm.kde.sc[2] = NEG_HALF_LOG2E/(h*h);
    sm.kde.sc[3] = poolw[0]*mean + poolw[1]*r.y;
  }
  __syncthreads();
  float lo = sm.kde.sc[0], st = sm.kde.sc[1], kk = sm.kde.sc[2];
  float gv = lo + st*(float)t;
  float acc = 0.f;
  if (t < GRID_PTS){
    float c0 = kk*gv*gv, c1 = -2.f*kk*gv;
    const float4* p4 = (const float4*)sm.kde.xs;
    #pragma unroll 4
    for (int i=0;i<NG/2;++i){
      float4 s2 = p4[i];
      acc += fexp2(fmaf(kk, s2.y, fmaf(c1, s2.x, c0)));
      acc += fexp2(fmaf(kk, s2.w, fmaf(c1, s2.z, c0)));
    }
  }
  // inclusive scan
  float sv = acc;
  #pragma unroll
  for (int off=1; off<64; off<<=1){
    float n = __shfl_up(sv, off, 64);
    if (lane >= off) sv += n;
  }
  if (lane==63) sm.kde.wsum[wave] = sv;
  __syncthreads();
  if (t==0){
    float r2 = 0.f;
    #pragma unroll
    for (int i=0;i<8;++i){ sm.kde.woff[i]=r2; r2+=sm.kde.wsum[i]; }
    sm.kde.woff[8]=r2;
  }
  if (t < QN*8){ ((float*)sm.kde.redw)[t]=0.f; ((float*)sm.kde.redg)[t]=0.f; }
  __syncthreads();
  float invt = 1.f/fmaxf(sm.kde.woff[8], 1e-8f);
  float c = (sv + sm.kde.woff[wave]) * invt;
  float cw0 = __shfl(c, 0, 64), cw1 = __shfl(c, 63, 64);
  int qlo = max(0, (int)ceilf((cw0 - 0.17f)*(float)(QN-1)));
  int qhi = min(QN-1, (int)floorf((cw1 + 0.17f)*(float)(QN-1)));
  for (int q=qlo; q<=qhi; ++q){
    float w = 0.f;
    if (t < GRID_PTS){
      float dist = fabsf(c - (float)q*(1.f/(QN-1)));
      w = frcp(1.f + fexp2(SIG_K*dist));
    }
    float gw = gv*w;
    #pragma unroll
    for (int m=32;m>0;m>>=1){
      w  += __shfl_xor(w,  m, 64);
      gw += __shfl_xor(gw, m, 64);
    }
    if (lane==0){ sm.kde.redw[q][wave]=w; sm.kde.redg[q][wave]=gw; }
  }
  __syncthreads();
  if (t < QN){
    float sw=0.f, sgw=0.f;
    #pragma unroll
    for (int i=0;i<8;++i){ sw+=sm.kde.redw[t][i]; sgw+=sm.kde.redg[t][i]; }
    sm.kde.qs[t] = sgw / (sw + 1e-8f);
  }
  __syncthreads();
  if (t < ODIM){
    float a = 0.f;
    const float* kwb = kW + (size_t)d*QN*ODIM + t;
    #pragma unroll
    for (int q=0;q<QN;++q) a += sm.kde.qs[q]*kwb[q*ODIM];
    if (d==0) a += kb[t];
    atomicAdd(&kacc[g*ODIM + t], a);
    float bb = sm.kde.sc[3]*lpW[d*ODIM + t];
    if (d==0) bb += lpb[t];
    atomicAdd(&macc[g*ODIM + t], bb);
  }
  __syncthreads();   // protect union before next phase
}

// ---------------- x@W + logits phase (4 nodes per block) ----------------
__device__ void xw_phase(Smem& sm, const float* __restrict__ cur, int do_relu,
        const float* __restrict__ W, const float* __restrict__ as_, const float* __restrict__ ad_,
        float* __restrict__ xh, float* __restrict__ als, float* __restrict__ ald,
        int do_fill, const int* __restrict__ src, const int* __restrict__ dst,
        int* __restrict__ pos, int* __restrict__ csr){
  int t = threadIdx.x;
  if (do_fill && t < 64){
    int e = blockIdx.x*64 + t;
    int dd = dst[e];
    int pp = atomicAdd(&pos[dd], 1);
    if (pp < MAXE) csr[dd*MAXE + pp] = src[e];
  }
  int ln = t >> 7, j = t & 127;
  int n = blockIdx.x*4 + ln;
  float v = cur[(size_t)n*HC + j];
  if (do_relu) v = fmaxf(v, 0.f);
  sm.xw.rows[ln][j] = v;
  __syncthreads();
  float acc = 0.f;
  #pragma unroll 8
  for (int c2=0;c2<HC;++c2)
    acc += sm.xw.rows[ln][c2]*W[(size_t)c2*HC + j];
  xh[(size_t)n*HC + j] = acc;
  int h = j >> 5, cc = j & 31;
  float ps = acc*as_[h*HID+cc], pd = acc*ad_[h*HID+cc];
  #pragma unroll
  for (int m=16;m>0;m>>=1){
    ps += __shfl_xor(ps, m, 32);
    pd += __shfl_xor(pd, m, 32);
  }
  if (cc==0){ als[n*HEADS+h]=ps; ald[n*HEADS+h]=pd; }
  __syncthreads();
}

// ---------------- gather phase (4 dst nodes per block) ----------------
__device__ void gather_phase(Smem& sm, const int* __restrict__ csr, const int* __restrict__ pos,
        const float* __restrict__ als, const float* __restrict__ ald,
        const float* __restrict__ xh, const float* __restrict__ bias,
        float* __restrict__ out){
  int t = threadIdx.x;
  int sub = t >> 7, tl = t & 127;
  int d = blockIdx.x*4 + sub;
  int deg = min(pos[d], MAXE-1);
  int E = deg + 1;                       // + self loop
  const int* base = csr + d*MAXE;
  float a0 = ald[d*4+0], a1 = ald[d*4+1], a2 = ald[d*4+2], a3 = ald[d*4+3];
  for (int i=tl; i<E; i+=128){
    int s = (i < deg) ? base[i] : d;
    sm.gat.ssrc[sub][i] = s;
    float e0 = als[s*4+0]+a0, e1 = als[s*4+1]+a1, e2 = als[s*4+2]+a2, e3 = als[s*4+3]+a3;
    e0 = (e0>=0.f)? e0 : 0.2f*e0;
    e1 = (e1>=0.f)? e1 : 0.2f*e1;
    e2 = (e2>=0.f)? e2 : 0.2f*e2;
    e3 = (e3>=0.f)? e3 : 0.2f*e3;
    sm.gat.sexp[sub][i][0]=e0; sm.gat.sexp[sub][i][1]=e1;
    sm.gat.sexp[sub][i][2]=e2; sm.gat.sexp[sub][i][3]=e3;
  }
  __syncthreads();
  if (tl < HEADS){
    float m = -INFINITY;
    for (int i=0;i<E;++i) m = fmaxf(m, sm.gat.sexp[sub][i][tl]);
    sm.gat.smax[sub][tl] = m;
  }
  __syncthreads();
  for (int i=tl; i<E; i+=128){
    #pragma unroll
    for (int h=0;h<HEADS;++h)
      sm.gat.sexp[sub][i][h] = fexp2(LOG2E*(sm.gat.sexp[sub][i][h]-sm.gat.smax[sub][h]));
  }
  __syncthreads();
  if (tl < HEADS){
    float sdn = 0.f;
    for (int i=0;i<E;++i) sdn += sm.gat.sexp[sub][i][tl];
    sm.gat.sfac[sub][tl] = 1.f/(sdn + 1e-16f);
  }
  __syncthreads();
  int h = tl >> 5;
  float fac = sm.gat.sfac[sub][h];
  float acc = bias[tl];
  for (int i=0;i<E;++i)
    acc += sm.gat.sexp[sub][i][h]*fac * xh[(size_t)sm.gat.ssrc[sub][i]*HC + tl];
  out[(size_t)d*HC + tl] = acc;
  __syncthreads();
}

// ================= cooperative mega-kernel =================
__global__ __launch_bounds__(512, 4) void k_all(Params p){
  cg::grid_group grid = cg::this_grid();
  __shared__ Smem sm;
  int t = threadIdx.x, b = blockIdx.x;

  // phase 0: zero pos[2048] + macc/kacc[768]
  if (b < 8){
    int i = b*512 + t;
    if (i < 2048) p.pos[i] = 0;
    else if (i < 2816) p.macc[i-2048] = 0.f;   // macc(384)+kacc(384) contiguous
  }
  grid.sync();

  // layer 0: readout(x) + x@W + CSR fill
  kde_phase(sm, p.x, 0, p.kW[0], p.kb[0], p.kacc, p.lpW[0], p.lpb[0], p.poolw, p.macc);
  xw_phase (sm, p.x, 0, p.W[0], p.As[0], p.Ad[0], p.xh, p.als, p.ald, 1, p.src, p.dst, p.pos, p.csr);
  grid.sync();
  gather_phase(sm, p.csr, p.pos, p.als, p.ald, p.xh, p.Bi[0], p.cur1);
  grid.sync();

  // layer 1 (relu fused into loads)
  kde_phase(sm, p.cur1, 1, p.kW[1], p.kb[1], p.kacc+128, p.lpW[1], p.lpb[1], p.poolw, p.macc+128);
  xw_phase (sm, p.cur1, 1, p.W[1], p.As[1], p.Ad[1], p.xh, p.als, p.ald, 0, nullptr, nullptr, nullptr, nullptr);
  grid.sync();
  gather_phase(sm, p.csr, p.pos, p.als, p.ald, p.xh, p.Bi[1], p.cur2);
  grid.sync();

  // readout 2
  kde_phase(sm, p.cur2, 0, p.kW[2], p.kb[2], p.kacc+256, p.lpW[2], p.lpb[2], p.poolw, p.macc+256);
  grid.sync();

  // final risk
  if (b == 0){
    float* sdm = (float*)&sm;
    if (t < 128){
      float s3 = p.macc[t]+p.macc[t+128]+p.macc[t+256]
               + p.kacc[t]+p.kacc[t+128]+p.kacc[t+256];
      sdm[t] = s3 * (1.f/3.f) * p.beta[t & 31];
    }
    __syncthreads();
    if (t < 128 && (t & 31) == 0){
      int g = t >> 5;
      float s = 0.f;
      #pragma unroll
      for (int i=0;i<32;++i) s += sdm[g*32+i];
      p.out[g] = s + p.h0[0];
    }
  }
}

// ================= fallback multi-launch kernels (round-5 path) =================
__global__ __launch_bounds__(1024) void k_zero(int* __restrict__ pos, float* __restrict__ acc){
  int t = threadIdx.x;
  pos[t] = 0; pos[t+1024] = 0;
  if (t < 768) acc[t] = 0.f;
}

__global__ __launch_bounds__(512) void k_layer(Params p, const float* cur, int do_relu, int li,
                                               int do_fill, float* outnul){
  (void)outnul;
  __shared__ Smem sm;
  if (blockIdx.x < 512){
    // remap block for kde (blockIdx used inside kde_phase is fine: b<512)
    kde_phase(sm, cur, do_relu, p.kW[li], p.kb[li], p.kacc+li*128,
              p.lpW[li], p.lpb[li], p.poolw, p.macc+li*128);
  } else if (li < 2){
    // xw path with shifted block index: emulate by direct code (4 nodes/block over b2)
    int b2 = blockIdx.x - 512;
    int t = threadIdx.x;
    if (do_fill && t < 64){
      int e = b2*64 + t;
      int dd = p.dst[e];
      int pp = atomicAdd(&p.pos[dd], 1);
      if (pp < MAXE) p.csr[dd*MAXE + pp] = p.src[e];
    }
    int ln = t >> 7, j = t & 127;
    int n = b2*4 + ln;
    float v = cur[(size_t)n*HC + j];
    if (do_relu) v = fmaxf(v, 0.f);
    sm.xw.rows[ln][j] = v;
    __syncthreads();
    float acc = 0.f;
    #pragma unroll 8
    for (int c2=0;c2<HC;++c2)
      acc += sm.xw.rows[ln][c2]*p.W[li][(size_t)c2*HC + j];
    p.xh[(size_t)n*HC + j] = acc;
    int h = j >> 5, cc = j & 31;
    float ps = acc*p.As[li][h*HID+cc], pd = acc*p.Ad[li][h*HID+cc];
    #pragma unroll
    for (int m=16;m>0;m>>=1){
      ps += __shfl_xor(ps, m, 32);
      pd += __shfl_xor(pd, m, 32);
    }
    if (cc==0){ p.als[n*HEADS+h]=ps; p.ald[n*HEADS+h]=pd; }
  }
}

__global__ __launch_bounds__(512) void k_gather_f(Params p, int li, float* outb){
  __shared__ Smem sm;
  gather_phase(sm, p.csr, p.pos, p.als, p.ald, p.xh, p.Bi[li], outb);
}

__global__ void k_final_f(Params p){
  int t = threadIdx.x;
  __shared__ float sdm[128];
  float s3 = p.macc[t]+p.macc[t+128]+p.macc[t+256]
           + p.kacc[t]+p.kacc[t+128]+p.kacc[t+256];
  sdm[t] = s3 * (1.f/3.f) * p.beta[t & 31];
  __syncthreads();
  if ((t & 31) == 0){
    int g = t >> 5;
    float s = 0.f;
    #pragma unroll
    for (int i=0;i<32;++i) s += sdm[g*32+i];
    p.out[g] = s + p.h0[0];
  }
}

extern "C" void kernel_launch(void* const* d_in, const int* in_sizes, int n_in,
                              void* d_out, int out_size, void* d_ws, size_t ws_size,
                              hipStream_t stream) {
  (void)in_sizes; (void)n_in; (void)out_size; (void)ws_size;
  Params p;
  p.x   = (const float*)d_in[0];
  const int* ei = (const int*)d_in[1];
  p.src = ei; p.dst = ei + EE;
  p.W[0]=(const float*)d_in[3];  p.As[0]=(const float*)d_in[4];
  p.Ad[0]=(const float*)d_in[5]; p.Bi[0]=(const float*)d_in[6];
  p.W[1]=(const float*)d_in[7];  p.As[1]=(const float*)d_in[8];
  p.Ad[1]=(const float*)d_in[9]; p.Bi[1]=(const float*)d_in[10];
  p.lpW[0]=(const float*)d_in[11]; p.lpb[0]=(const float*)d_in[12];
  p.lpW[1]=(const float*)d_in[13]; p.lpb[1]=(const float*)d_in[14];
  p.lpW[2]=(const float*)d_in[15]; p.lpb[2]=(const float*)d_in[16];
  p.kW[0]=(const float*)d_in[17]; p.kb[0]=(const float*)d_in[18];
  p.kW[1]=(const float*)d_in[19]; p.kb[1]=(const float*)d_in[20];
  p.kW[2]=(const float*)d_in[21]; p.kb[2]=(const float*)d_in[22];
  p.poolw=(const float*)d_in[23]; p.beta=(const float*)d_in[24]; p.h0=(const float*)d_in[25];
  p.out = (float*)d_out;

  float* ws = (float*)d_ws;
  p.cur1 = ws;                   // 262144
  p.cur2 = p.cur1 + 262144;      // 262144
  p.xh   = p.cur2 + 262144;      // 262144
  p.als  = p.xh + 262144;        // 8192
  p.ald  = p.als + 8192;         // 8192
  p.macc = p.ald + 8192;         // 384
  p.kacc = p.macc + 384;         // 384
  p.pos  = (int*)(p.kacc + 384); // 2048
  p.csr  = p.pos + 2048;         // 2048*160

  void* kargs[] = { (void*)&p };
  hipError_t err = hipLaunchCooperativeKernel((void*)k_all, dim3(NBLK), dim3(512),
                                              kargs, 0, stream);
  if (err != hipSuccess){
    // fallback: round-5 multi-launch path
    k_zero<<<1, 1024, 0, stream>>>(p.pos, p.macc);
    k_layer<<<1024, 512, 0, stream>>>(p, p.x, 0, 0, 1, nullptr);
    k_gather_f<<<NBLK, 512, 0, stream>>>(p, 0, p.cur1);
    k_layer<<<1024, 512, 0, stream>>>(p, p.cur1, 1, 1, 0, nullptr);
    k_gather_f<<<NBLK, 512, 0, stream>>>(p, 1, p.cur2);
    k_layer<<<512, 512, 0, stream>>>(p, p.cur2, 0, 2, 0, nullptr);
    k_final_f<<<1, 128, 0, stream>>>(p);
  }
}

// Round 8
// 257.412 us; speedup vs baseline: 2.0954x; 2.0954x over previous
//
#include <hip/hip_runtime.h>
#include <math.h>

// ---- static config (mirror of reference) ----
#define GNUM 4
#define NG 512
#define NN 2048
#define EE 32768
#define HC 128
#define HEADS 4
#define HID 32
#define GRID_PTS 500
#define QN 20
#define ODIM 32
#define MAXE 160              // per-dst edge cap (deg ~ Poisson(16); P(>159) ~ 0)
#define NBLK 512

#define LOG2E 1.44269504088896340736f
#define NEG_HALF_LOG2E -0.72134752044448170368f
#define N_POW_M02 0.2871745887492588f   // 512^-0.2
#define SIG_K 144.269504089f            // 100 * log2(e)

__device__ __forceinline__ float fexp2(float x){ return __builtin_amdgcn_exp2f(x); }
__device__ __forceinline__ float frcp(float x){ return __builtin_amdgcn_rcpf(x); }

struct SmemKDE {
  __align__(16) float2 xs[NG];   // (x, x^2) 4KB
  float4 wred4[8];
  float sc[4];
  float wsum[8], woff[9];
  float redw[QN][8], redg[QN][8];
  float qs[QN];
};
struct SmemXW  { float rows[4][HC]; };
struct SmemGat {
  int   ssrc[4][MAXE];
  float sexp[4][MAXE][HEADS];
  float smax[4][HEADS], sfac[4][HEADS];
};
union Smem { SmemKDE kde; SmemXW xw; SmemGat gat; };

// ---------------- KDE readout phase (one (g,d) per block; requires blockIdx<512) ----------------
__device__ void kde_phase(Smem& sm, const float* __restrict__ cur, int do_relu,
        const float* __restrict__ kW, const float* __restrict__ kb, float* __restrict__ kacc,
        const float* __restrict__ lpW, const float* __restrict__ lpb,
        const float* __restrict__ poolw, float* __restrict__ macc){
  int b = blockIdx.x;
  int g = b >> 7, d = b & 127;
  int t = threadIdx.x;
  int lane = t & 63, wave = t >> 6;
  float v = cur[((size_t)g*NG + t)*HC + d];
  if (do_relu) v = fmaxf(v, 0.f);
  sm.kde.xs[t] = make_float2(v, v*v);
  float mn=v, mx=v, smv=v, sq=v*v;
  #pragma unroll
  for (int m=32; m>0; m>>=1){
    mn = fminf(mn, __shfl_xor(mn, m, 64));
    mx = fmaxf(mx, __shfl_xor(mx, m, 64));
    smv += __shfl_xor(smv, m, 64);
    sq += __shfl_xor(sq, m, 64);
  }
  if (lane==0) sm.kde.wred4[wave] = make_float4(mn,mx,smv,sq);
  __syncthreads();
  if (t==0){
    float4 r = sm.kde.wred4[0];
    #pragma unroll
    for (int i=1;i<8;++i){
      float4 bb = sm.kde.wred4[i];
      r.x = fminf(r.x,bb.x); r.y = fmaxf(r.y,bb.y); r.z += bb.z; r.w += bb.w;
    }
    float mean = r.z * (1.f/NG);
    float var  = fmaxf(r.w*(1.f/NG) - mean*mean, 0.f);
    float sd   = sqrtf(var) + (1e-8f/3.f);
    float h    = 1.06f * sd * N_POW_M02;
    float lo = r.x - 1e-6f, hi = r.y + 1e-6f;
    sm.kde.sc[0] = lo;
    sm.kde.sc[1] = (hi-lo)*(1.f/(GRID_PTS-1));
    sm.kde.sc[2] = NEG_HALF_LOG2E/(h*h);
    sm.kde.sc[3] = poolw[0]*mean + poolw[1]*r.y;
  }
  __syncthreads();
  float lo = sm.kde.sc[0], st = sm.kde.sc[1], kk = sm.kde.sc[2];
  float gv = lo + st*(float)t;
  float acc = 0.f;
  if (t < GRID_PTS){
    float c0 = kk*gv*gv, c1 = -2.f*kk*gv;
    const float4* p4 = (const float4*)sm.kde.xs;
    #pragma unroll 4
    for (int i=0;i<NG/2;++i){
      float4 s2 = p4[i];
      acc += fexp2(fmaf(kk, s2.y, fmaf(c1, s2.x, c0)));
      acc += fexp2(fmaf(kk, s2.w, fmaf(c1, s2.z, c0)));
    }
  }
  // inclusive scan
  float sv = acc;
  #pragma unroll
  for (int off=1; off<64; off<<=1){
    float n = __shfl_up(sv, off, 64);
    if (lane >= off) sv += n;
  }
  if (lane==63) sm.kde.wsum[wave] = sv;
  __syncthreads();
  if (t==0){
    float r2 = 0.f;
    #pragma unroll
    for (int i=0;i<8;++i){ sm.kde.woff[i]=r2; r2+=sm.kde.wsum[i]; }
    sm.kde.woff[8]=r2;
  }
  if (t < QN*8){ ((float*)sm.kde.redw)[t]=0.f; ((float*)sm.kde.redg)[t]=0.f; }
  __syncthreads();
  float invt = 1.f/fmaxf(sm.kde.woff[8], 1e-8f);
  float c = (sv + sm.kde.woff[wave]) * invt;
  float cw0 = __shfl(c, 0, 64), cw1 = __shfl(c, 63, 64);
  int qlo = max(0, (int)ceilf((cw0 - 0.17f)*(float)(QN-1)));
  int qhi = min(QN-1, (int)floorf((cw1 + 0.17f)*(float)(QN-1)));
  for (int q=qlo; q<=qhi; ++q){
    float w = 0.f;
    if (t < GRID_PTS){
      float dist = fabsf(c - (float)q*(1.f/(QN-1)));
      w = frcp(1.f + fexp2(SIG_K*dist));
    }
    float gw = gv*w;
    #pragma unroll
    for (int m=32;m>0;m>>=1){
      w  += __shfl_xor(w,  m, 64);
      gw += __shfl_xor(gw, m, 64);
    }
    if (lane==0){ sm.kde.redw[q][wave]=w; sm.kde.redg[q][wave]=gw; }
  }
  __syncthreads();
  if (t < QN){
    float sw=0.f, sgw=0.f;
    #pragma unroll
    for (int i=0;i<8;++i){ sw+=sm.kde.redw[t][i]; sgw+=sm.kde.redg[t][i]; }
    sm.kde.qs[t] = sgw / (sw + 1e-8f);
  }
  __syncthreads();
  if (t < ODIM){
    float a = 0.f;
    const float* kwb = kW + (size_t)d*QN*ODIM + t;
    #pragma unroll
    for (int q=0;q<QN;++q) a += sm.kde.qs[q]*kwb[q*ODIM];
    if (d==0) a += kb[t];
    atomicAdd(&kacc[g*ODIM + t], a);
    float bb = sm.kde.sc[3]*lpW[d*ODIM + t];
    if (d==0) bb += lpb[t];
    atomicAdd(&macc[g*ODIM + t], bb);
  }
  __syncthreads();
}

// ---------------- gather core (4 dst/block; returns this thread's channel value) ----------------
__device__ float gather_core(Smem& sm, int d, int sub, int tl,
        const int* __restrict__ csr, const int* __restrict__ pos,
        const float* __restrict__ als, const float* __restrict__ ald,
        const float* __restrict__ xh, const float* __restrict__ bias){
  int deg = min(pos[d], MAXE-1);
  int E = deg + 1;                       // + self loop
  const int* base = csr + d*MAXE;
  float a0 = ald[d*4+0], a1 = ald[d*4+1], a2 = ald[d*4+2], a3 = ald[d*4+3];
  for (int i=tl; i<E; i+=128){
    int s = (i < deg) ? base[i] : d;
    sm.gat.ssrc[sub][i] = s;
    float e0 = als[s*4+0]+a0, e1 = als[s*4+1]+a1, e2 = als[s*4+2]+a2, e3 = als[s*4+3]+a3;
    e0 = (e0>=0.f)? e0 : 0.2f*e0;
    e1 = (e1>=0.f)? e1 : 0.2f*e1;
    e2 = (e2>=0.f)? e2 : 0.2f*e2;
    e3 = (e3>=0.f)? e3 : 0.2f*e3;
    sm.gat.sexp[sub][i][0]=e0; sm.gat.sexp[sub][i][1]=e1;
    sm.gat.sexp[sub][i][2]=e2; sm.gat.sexp[sub][i][3]=e3;
  }
  __syncthreads();
  if (tl < HEADS){
    float m = -INFINITY;
    for (int i=0;i<E;++i) m = fmaxf(m, sm.gat.sexp[sub][i][tl]);
    sm.gat.smax[sub][tl] = m;
  }
  __syncthreads();
  for (int i=tl; i<E; i+=128){
    #pragma unroll
    for (int h=0;h<HEADS;++h)
      sm.gat.sexp[sub][i][h] = fexp2(LOG2E*(sm.gat.sexp[sub][i][h]-sm.gat.smax[sub][h]));
  }
  __syncthreads();
  if (tl < HEADS){
    float sdn = 0.f;
    for (int i=0;i<E;++i) sdn += sm.gat.sexp[sub][i][tl];
    sm.gat.sfac[sub][tl] = 1.f/(sdn + 1e-16f);
  }
  __syncthreads();
  int h = tl >> 5;
  float fac = sm.gat.sfac[sub][h];
  float acc = bias[tl];
  for (int i=0;i<E;++i)
    acc += sm.gat.sexp[sub][i][h]*fac * xh[(size_t)sm.gat.ssrc[sub][i]*HC + tl];
  __syncthreads();                        // gat LDS free for reuse after this
  return acc;
}

// ---------------- xw helper: GEMV row (in LDS rows[sub]) -> xh + logits ----------------
__device__ void xw_emit(Smem& sm, int sub, int j, int n,
        const float* __restrict__ W, const float* __restrict__ as_, const float* __restrict__ ad_,
        float* __restrict__ xh, float* __restrict__ als, float* __restrict__ ald){
  float acc = 0.f;
  #pragma unroll 8
  for (int c2=0;c2<HC;++c2)
    acc += sm.xw.rows[sub][c2]*W[(size_t)c2*HC + j];
  xh[(size_t)n*HC + j] = acc;
  int h = j >> 5, cc = j & 31;
  float ps = acc*as_[h*HID+cc], pd = acc*ad_[h*HID+cc];
  #pragma unroll
  for (int m=16;m>0;m>>=1){
    ps += __shfl_xor(ps, m, 32);
    pd += __shfl_xor(pd, m, 32);
  }
  if (cc==0){ als[n*HEADS+h]=ps; ald[n*HEADS+h]=pd; }
}

// ================= zero: pos[2048] + macc/kacc[768] + cnt =================
__global__ __launch_bounds__(1024) void k_zero(int* __restrict__ pos, float* __restrict__ acc,
                                               int* __restrict__ cnt){
  int t = threadIdx.x;
  pos[t] = 0; pos[t+1024] = 0;
  if (t < 768) acc[t] = 0.f;
  if (t == 0) *cnt = 0;
}

// ================= L0: kde0(x) | xw0(x) + CSR fill =================
__global__ __launch_bounds__(512) void k_L0(const float* __restrict__ x,
        const float* __restrict__ kW, const float* __restrict__ kb, float* __restrict__ kacc,
        const float* __restrict__ lpW, const float* __restrict__ lpb,
        const float* __restrict__ poolw, float* __restrict__ macc,
        const float* __restrict__ W, const float* __restrict__ as_, const float* __restrict__ ad_,
        float* __restrict__ xh, float* __restrict__ als, float* __restrict__ ald,
        const int* __restrict__ src, const int* __restrict__ dst,
        int* __restrict__ pos, int* __restrict__ csr){
  __shared__ Smem sm;
  int t = threadIdx.x;
  if (blockIdx.x < 512){
    kde_phase(sm, x, 0, kW, kb, kacc, lpW, lpb, poolw, macc);
  } else {
    int b2 = blockIdx.x - 512;
    if (t < 64){
      int e = b2*64 + t;
      int dd = dst[e];
      int pp = atomicAdd(&pos[dd], 1);
      if (pp < MAXE) csr[dd*MAXE + pp] = src[e];
    }
    int sub = t >> 7, j = t & 127;
    int n = b2*4 + sub;
    sm.xw.rows[sub][j] = x[(size_t)n*HC + j];
    __syncthreads();
    xw_emit(sm, sub, j, n, W, as_, ad_, xh, als, ald);
  }
}

// ================= G0: gather0 -> cur1, + fused xw1 (separate output buffers!) =================
__global__ __launch_bounds__(512) void k_G0(const int* __restrict__ csr, const int* __restrict__ pos,
        const float* __restrict__ als_in, const float* __restrict__ ald_in,
        const float* __restrict__ xh_in, const float* __restrict__ bias,
        float* __restrict__ cur1,
        const float* __restrict__ W1, const float* __restrict__ as1, const float* __restrict__ ad1,
        float* __restrict__ xh2, float* __restrict__ als2, float* __restrict__ ald2){
  __shared__ Smem sm;
  int t = threadIdx.x;
  int sub = t >> 7, tl = t & 127;
  int d = blockIdx.x*4 + sub;
  float acc = gather_core(sm, d, sub, tl, csr, pos, als_in, ald_in, xh_in, bias);
  cur1[(size_t)d*HC + tl] = acc;
  sm.xw.rows[sub][tl] = fmaxf(acc, 0.f);   // relu for next layer's input
  __syncthreads();
  xw_emit(sm, sub, tl, d, W1, as1, ad1, xh2, als2, ald2);
}

// ================= L1: kde1(cur1, relu) | gather1 -> cur2 =================
__global__ __launch_bounds__(512) void k_L1(const float* __restrict__ cur1,
        const float* __restrict__ kW, const float* __restrict__ kb, float* __restrict__ kacc,
        const float* __restrict__ lpW, const float* __restrict__ lpb,
        const float* __restrict__ poolw, float* __restrict__ macc,
        const int* __restrict__ csr, const int* __restrict__ pos,
        const float* __restrict__ als2, const float* __restrict__ ald2,
        const float* __restrict__ xh2, const float* __restrict__ bias,
        float* __restrict__ cur2){
  __shared__ Smem sm;
  int t = threadIdx.x;
  if (blockIdx.x < 512){
    kde_phase(sm, cur1, 1, kW, kb, kacc, lpW, lpb, poolw, macc);
  } else {
    int sub = t >> 7, tl = t & 127;
    int d = (blockIdx.x - 512)*4 + sub;
    float acc = gather_core(sm, d, sub, tl, csr, pos, als2, ald2, xh2, bias);
    cur2[(size_t)d*HC + tl] = acc;
  }
}

// ================= L2: kde2(cur2) + last-block final =================
__global__ __launch_bounds__(512) void k_L2(const float* __restrict__ cur2,
        const float* __restrict__ kW, const float* __restrict__ kb, float* __restrict__ kacc,
        const float* __restrict__ lpW, const float* __restrict__ lpb,
        const float* __restrict__ poolw, float* __restrict__ macc,
        int* __restrict__ cnt, const float* __restrict__ maccA, const float* __restrict__ kaccA,
        const float* __restrict__ beta, const float* __restrict__ h0,
        float* __restrict__ out){
  __shared__ Smem sm;
  __shared__ int is_last;
  int t = threadIdx.x;
  kde_phase(sm, cur2, 0, kW, kb, kacc, lpW, lpb, poolw, macc);
  __threadfence();
  if (t == 0) is_last = (atomicAdd(cnt, 1) == NBLK-1);
  __syncthreads();
  if (is_last){
    float* sdm = (float*)&sm;
    if (t < 128){
      float s3 = 0.f;
      #pragma unroll
      for (int l=0;l<3;++l){
        s3 += __hip_atomic_load(&maccA[l*128+t], __ATOMIC_RELAXED, __HIP_MEMORY_SCOPE_AGENT);
        s3 += __hip_atomic_load(&kaccA[l*128+t], __ATOMIC_RELAXED, __HIP_MEMORY_SCOPE_AGENT);
      }
      sdm[t] = s3 * (1.f/3.f) * beta[t & 31];
    }
    __syncthreads();
    if (t < 128 && (t & 31) == 0){
      int g = t >> 5;
      float s = 0.f;
      #pragma unroll
      for (int i=0;i<32;++i) s += sdm[g*32+i];
      out[g] = s + h0[0];
    }
  }
}

extern "C" void kernel_launch(void* const* d_in, const int* in_sizes, int n_in,
                              void* d_out, int out_size, void* d_ws, size_t ws_size,
                              hipStream_t stream) {
  (void)in_sizes; (void)n_in; (void)out_size; (void)ws_size;
  const float* x    = (const float*)d_in[0];
  const int*   ei   = (const int*)d_in[1];
  const int*   srcp = ei;
  const int*   dstp = ei + EE;
  const float* W[2]   = {(const float*)d_in[3], (const float*)d_in[7]};
  const float* As[2]  = {(const float*)d_in[4], (const float*)d_in[8]};
  const float* Ad[2]  = {(const float*)d_in[5], (const float*)d_in[9]};
  const float* Bi[2]  = {(const float*)d_in[6], (const float*)d_in[10]};
  const float* lpW[3] = {(const float*)d_in[11], (const float*)d_in[13], (const float*)d_in[15]};
  const float* lpb[3] = {(const float*)d_in[12], (const float*)d_in[14], (const float*)d_in[16]};
  const float* kW[3]  = {(const float*)d_in[17], (const float*)d_in[19], (const float*)d_in[21]};
  const float* kb[3]  = {(const float*)d_in[18], (const float*)d_in[20], (const float*)d_in[22]};
  const float* poolw  = (const float*)d_in[23];
  const float* beta   = (const float*)d_in[24];
  const float* h0     = (const float*)d_in[25];
  float* out = (float*)d_out;

  // workspace layout (floats unless noted)
  float* ws = (float*)d_ws;
  float* cur1 = ws;                  // 262144
  float* cur2 = cur1 + 262144;       // 262144
  float* xh   = cur2 + 262144;       // 262144 (layer 0)
  float* xh2  = xh + 262144;         // 262144 (layer 1)
  float* als  = xh2 + 262144;        // 8192
  float* ald  = als + 8192;          // 8192
  float* als2 = ald + 8192;          // 8192
  float* ald2 = als2 + 8192;         // 8192
  float* macc = ald2 + 8192;         // 384 (3 slots x 128)
  float* kacc = macc + 384;          // 384
  int*   pos  = (int*)(kacc + 384);  // 2048
  int*   cnt  = pos + 2048;          // 1
  int*   csr  = cnt + 1;             // 2048*160

  k_zero<<<1, 1024, 0, stream>>>(pos, macc, cnt);
  k_L0<<<1024, 512, 0, stream>>>(x, kW[0], kb[0], kacc, lpW[0], lpb[0], poolw, macc,
                                 W[0], As[0], Ad[0], xh, als, ald,
                                 srcp, dstp, pos, csr);
  k_G0<<<512, 512, 0, stream>>>(csr, pos, als, ald, xh, Bi[0], cur1,
                                W[1], As[1], Ad[1], xh2, als2, ald2);
  k_L1<<<1024, 512, 0, stream>>>(cur1, kW[1], kb[1], kacc+128, lpW[1], lpb[1], poolw, macc+128,
                                 csr, pos, als2, ald2, xh2, Bi[1], cur2);
  k_L2<<<512, 512, 0, stream>>>(cur2, kW[2], kb[2], kacc+256, lpW[2], lpb[2], poolw, macc+256,
                                cnt, macc, kacc, beta, h0, out);
}

// Round 9
// 201.105 us; speedup vs baseline: 2.6821x; 1.2800x over previous
//
#include <hip/hip_runtime.h>
#include <math.h>

// ---- static config (mirror of reference) ----
#define GNUM 4
#define NG 512
#define NN 2048
#define EE 32768
#define HC 128
#define HEADS 4
#define HID 32
#define GRID_PTS 500
#define QN 20
#define ODIM 32
#define MAXE 160              // per-dst edge cap (deg ~ Poisson(16); P(>159) ~ 0)

#define LOG2E 1.44269504088896340736f
#define NEG_HALF_LOG2E -0.72134752044448170368f
#define N_POW_M02 0.2871745887492588f   // 512^-0.2
#define SIG_K 144.269504089f            // 100 * log2(e)

__device__ __forceinline__ float fexp2(float x){ return __builtin_amdgcn_exp2f(x); }
__device__ __forceinline__ float frcp(float x){ return __builtin_amdgcn_rcpf(x); }

struct SmemKDE {
  __align__(16) float2 xs[NG];   // (x, x^2) 4KB
  float4 wred4[8];
  float sc[4];
  float wsum[8], woff[9];
  float redw[QN][8], redg[QN][8];
  float qs[QN];
};
struct SmemXW  { float rows[4][HC]; };
struct SmemGat {
  int   ssrc[4][MAXE];
  float sexp[4][MAXE][HEADS];
  float smax[4][HEADS], sfac[4][HEADS];
};
union Smem { SmemKDE kde; SmemXW xw; SmemGat gat; };

// ---------------- KDE readout phase (one (g,d) per block; requires blockIdx<512) ----------------
// trans=1: cur is [channel][node] (coalesced reads). acc pointers are 4-way sharded by d>>5.
__device__ void kde_phase(Smem& sm, const float* __restrict__ cur, int do_relu, int trans,
        const float* __restrict__ kW, const float* __restrict__ kb, float* __restrict__ kacc,
        const float* __restrict__ lpW, const float* __restrict__ lpb,
        const float* __restrict__ poolw, float* __restrict__ macc){
  int b = blockIdx.x;
  int g = b >> 7, d = b & 127;
  int t = threadIdx.x;
  int lane = t & 63, wave = t >> 6;
  float v = trans ? cur[(size_t)d*NN + g*NG + t]
                  : cur[((size_t)g*NG + t)*HC + d];
  if (do_relu) v = fmaxf(v, 0.f);
  sm.kde.xs[t] = make_float2(v, v*v);
  float mn=v, mx=v, smv=v, sq=v*v;
  #pragma unroll
  for (int m=32; m>0; m>>=1){
    mn = fminf(mn, __shfl_xor(mn, m, 64));
    mx = fmaxf(mx, __shfl_xor(mx, m, 64));
    smv += __shfl_xor(smv, m, 64);
    sq += __shfl_xor(sq, m, 64);
  }
  if (lane==0) sm.kde.wred4[wave] = make_float4(mn,mx,smv,sq);
  __syncthreads();
  if (t==0){
    float4 r = sm.kde.wred4[0];
    #pragma unroll
    for (int i=1;i<8;++i){
      float4 bb = sm.kde.wred4[i];
      r.x = fminf(r.x,bb.x); r.y = fmaxf(r.y,bb.y); r.z += bb.z; r.w += bb.w;
    }
    float mean = r.z * (1.f/NG);
    float var  = fmaxf(r.w*(1.f/NG) - mean*mean, 0.f);
    float sd   = sqrtf(var) + (1e-8f/3.f);
    float h    = 1.06f * sd * N_POW_M02;
    float lo = r.x - 1e-6f, hi = r.y + 1e-6f;
    sm.kde.sc[0] = lo;
    sm.kde.sc[1] = (hi-lo)*(1.f/(GRID_PTS-1));
    sm.kde.sc[2] = NEG_HALF_LOG2E/(h*h);
    sm.kde.sc[3] = poolw[0]*mean + poolw[1]*r.y;
  }
  __syncthreads();
  float lo = sm.kde.sc[0], st = sm.kde.sc[1], kk = sm.kde.sc[2];
  float gv = lo + st*(float)t;
  float acc = 0.f;
  if (t < GRID_PTS){
    float c0 = kk*gv*gv, c1 = -2.f*kk*gv;
    const float4* p4 = (const float4*)sm.kde.xs;
    #pragma unroll 4
    for (int i=0;i<NG/2;++i){
      float4 s2 = p4[i];
      acc += fexp2(fmaf(kk, s2.y, fmaf(c1, s2.x, c0)));
      acc += fexp2(fmaf(kk, s2.w, fmaf(c1, s2.z, c0)));
    }
  }
  // inclusive scan
  float sv = acc;
  #pragma unroll
  for (int off=1; off<64; off<<=1){
    float n = __shfl_up(sv, off, 64);
    if (lane >= off) sv += n;
  }
  if (lane==63) sm.kde.wsum[wave] = sv;
  __syncthreads();
  if (t==0){
    float r2 = 0.f;
    #pragma unroll
    for (int i=0;i<8;++i){ sm.kde.woff[i]=r2; r2+=sm.kde.wsum[i]; }
    sm.kde.woff[8]=r2;
  }
  if (t < QN*8){ ((float*)sm.kde.redw)[t]=0.f; ((float*)sm.kde.redg)[t]=0.f; }
  __syncthreads();
  float invt = 1.f/fmaxf(sm.kde.woff[8], 1e-8f);
  float c = (sv + sm.kde.woff[wave]) * invt;
  float cw0 = __shfl(c, 0, 64), cw1 = __shfl(c, 63, 64);
  int qlo = max(0, (int)ceilf((cw0 - 0.17f)*(float)(QN-1)));
  int qhi = min(QN-1, (int)floorf((cw1 + 0.17f)*(float)(QN-1)));
  for (int q=qlo; q<=qhi; ++q){
    float w = 0.f;
    if (t < GRID_PTS){
      float dist = fabsf(c - (float)q*(1.f/(QN-1)));
      w = frcp(1.f + fexp2(SIG_K*dist));
    }
    float gw = gv*w;
    #pragma unroll
    for (int m=32;m>0;m>>=1){
      w  += __shfl_xor(w,  m, 64);
      gw += __shfl_xor(gw, m, 64);
    }
    if (lane==0){ sm.kde.redw[q][wave]=w; sm.kde.redg[q][wave]=gw; }
  }
  __syncthreads();
  if (t < QN){
    float sw=0.f, sgw=0.f;
    #pragma unroll
    for (int i=0;i<8;++i){ sw+=sm.kde.redw[t][i]; sgw+=sm.kde.redg[t][i]; }
    sm.kde.qs[t] = sgw / (sw + 1e-8f);
  }
  __syncthreads();
  if (t < ODIM){
    int shard = (d >> 5) & 3;              // 4-way contention sharding
    float a = 0.f;
    const float* kwb = kW + (size_t)d*QN*ODIM + t;
    #pragma unroll
    for (int q=0;q<QN;++q) a += sm.kde.qs[q]*kwb[q*ODIM];
    if (d==0) a += kb[t];
    atomicAdd(&kacc[shard*128 + g*ODIM + t], a);
    float bb = sm.kde.sc[3]*lpW[d*ODIM + t];
    if (d==0) bb += lpb[t];
    atomicAdd(&macc[shard*128 + g*ODIM + t], bb);
  }
  __syncthreads();
}

// ---------------- gather core (4 dst/block; returns this thread's channel value) ----------------
__device__ float gather_core(Smem& sm, int d, int sub, int tl,
        const int* __restrict__ csr, const int* __restrict__ pos,
        const float* __restrict__ als, const float* __restrict__ ald,
        const float* __restrict__ xh, const float* __restrict__ bias){
  int deg = min(pos[d], MAXE-1);
  int E = deg + 1;                       // + self loop
  const int* base = csr + d*MAXE;
  float a0 = ald[d*4+0], a1 = ald[d*4+1], a2 = ald[d*4+2], a3 = ald[d*4+3];
  for (int i=tl; i<E; i+=128){
    int s = (i < deg) ? base[i] : d;
    sm.gat.ssrc[sub][i] = s;
    float e0 = als[s*4+0]+a0, e1 = als[s*4+1]+a1, e2 = als[s*4+2]+a2, e3 = als[s*4+3]+a3;
    e0 = (e0>=0.f)? e0 : 0.2f*e0;
    e1 = (e1>=0.f)? e1 : 0.2f*e1;
    e2 = (e2>=0.f)? e2 : 0.2f*e2;
    e3 = (e3>=0.f)? e3 : 0.2f*e3;
    sm.gat.sexp[sub][i][0]=e0; sm.gat.sexp[sub][i][1]=e1;
    sm.gat.sexp[sub][i][2]=e2; sm.gat.sexp[sub][i][3]=e3;
  }
  __syncthreads();
  if (tl < HEADS){
    float m = -INFINITY;
    for (int i=0;i<E;++i) m = fmaxf(m, sm.gat.sexp[sub][i][tl]);
    sm.gat.smax[sub][tl] = m;
  }
  __syncthreads();
  for (int i=tl; i<E; i+=128){
    #pragma unroll
    for (int h=0;h<HEADS;++h)
      sm.gat.sexp[sub][i][h] = fexp2(LOG2E*(sm.gat.sexp[sub][i][h]-sm.gat.smax[sub][h]));
  }
  __syncthreads();
  if (tl < HEADS){
    float sdn = 0.f;
    for (int i=0;i<E;++i) sdn += sm.gat.sexp[sub][i][tl];
    sm.gat.sfac[sub][tl] = 1.f/(sdn + 1e-16f);
  }
  __syncthreads();
  int h = tl >> 5;
  float fac = sm.gat.sfac[sub][h];
  float acc = bias[tl];
  for (int i=0;i<E;++i)
    acc += sm.gat.sexp[sub][i][h]*fac * xh[(size_t)sm.gat.ssrc[sub][i]*HC + tl];
  __syncthreads();                        // gat LDS free for reuse after this
  return acc;
}

// ---------------- xw helper: GEMV row (in LDS rows[sub]) -> xh + logits ----------------
__device__ void xw_emit(Smem& sm, int sub, int j, int n,
        const float* __restrict__ W, const float* __restrict__ as_, const float* __restrict__ ad_,
        float* __restrict__ xh, float* __restrict__ als, float* __restrict__ ald){
  float acc = 0.f;
  #pragma unroll 8
  for (int c2=0;c2<HC;++c2)
    acc += sm.xw.rows[sub][c2]*W[(size_t)c2*HC + j];
  xh[(size_t)n*HC + j] = acc;
  int h = j >> 5, cc = j & 31;
  float ps = acc*as_[h*HID+cc], pd = acc*ad_[h*HID+cc];
  #pragma unroll
  for (int m=16;m>0;m>>=1){
    ps += __shfl_xor(ps, m, 32);
    pd += __shfl_xor(pd, m, 32);
  }
  if (cc==0){ als[n*HEADS+h]=ps; ald[n*HEADS+h]=pd; }
}

// ---------------- transpose write: rows[4][128] -> curT[c][n0..n0+3] as float4 ----------------
__device__ void write_transposed(Smem& sm, int t, int n0, float* __restrict__ curT){
  if (t < HC){
    float4 v = make_float4(sm.xw.rows[0][t], sm.xw.rows[1][t],
                           sm.xw.rows[2][t], sm.xw.rows[3][t]);
    *(float4*)(curT + (size_t)t*NN + n0) = v;
  }
}

// ================= zero: pos[2048] + maccS[1536] + kaccS[1536] =================
__global__ __launch_bounds__(1024) void k_zero(int* __restrict__ pos, float* __restrict__ acc){
  int t = threadIdx.x;
  pos[t] = 0; pos[t+1024] = 0;
  acc[t] = 0.f; acc[t+1024] = 0.f;
  if (t < 1024) acc[t+2048] = 0.f;
}

// ================= L0: kde0(x, scattered) | xw0(x) + CSR fill =================
__global__ __launch_bounds__(512) void k_L0(const float* __restrict__ x,
        const float* __restrict__ kW, const float* __restrict__ kb, float* __restrict__ kacc,
        const float* __restrict__ lpW, const float* __restrict__ lpb,
        const float* __restrict__ poolw, float* __restrict__ macc,
        const float* __restrict__ W, const float* __restrict__ as_, const float* __restrict__ ad_,
        float* __restrict__ xh, float* __restrict__ als, float* __restrict__ ald,
        const int* __restrict__ src, const int* __restrict__ dst,
        int* __restrict__ pos, int* __restrict__ csr){
  __shared__ Smem sm;
  int t = threadIdx.x;
  if (blockIdx.x < 512){
    kde_phase(sm, x, 0, 0, kW, kb, kacc, lpW, lpb, poolw, macc);
  } else {
    int b2 = blockIdx.x - 512;
    if (t < 64){
      int e = b2*64 + t;
      int dd = dst[e];
      int pp = atomicAdd(&pos[dd], 1);
      if (pp < MAXE) csr[dd*MAXE + pp] = src[e];
    }
    int sub = t >> 7, j = t & 127;
    int n = b2*4 + sub;
    sm.xw.rows[sub][j] = x[(size_t)n*HC + j];
    __syncthreads();
    xw_emit(sm, sub, j, n, W, as_, ad_, xh, als, ald);
  }
}

// ================= G0: gather0 -> cur1T (post-relu, transposed) + fused xw1 =================
__global__ __launch_bounds__(512) void k_G0(const int* __restrict__ csr, const int* __restrict__ pos,
        const float* __restrict__ als_in, const float* __restrict__ ald_in,
        const float* __restrict__ xh_in, const float* __restrict__ bias,
        float* __restrict__ cur1T,
        const float* __restrict__ W1, const float* __restrict__ as1, const float* __restrict__ ad1,
        float* __restrict__ xh2, float* __restrict__ als2, float* __restrict__ ald2){
  __shared__ Smem sm;
  int t = threadIdx.x;
  int sub = t >> 7, tl = t & 127;
  int d = blockIdx.x*4 + sub;
  float acc = gather_core(sm, d, sub, tl, csr, pos, als_in, ald_in, xh_in, bias);
  sm.xw.rows[sub][tl] = fmaxf(acc, 0.f);   // post-relu: input to both kde1 and xw1
  __syncthreads();
  write_transposed(sm, t, blockIdx.x*4, cur1T);
  xw_emit(sm, sub, tl, d, W1, as1, ad1, xh2, als2, ald2);
}

// ================= L1: kde1(cur1T, coalesced) | gather1 -> cur2T =================
__global__ __launch_bounds__(512) void k_L1(const float* __restrict__ cur1T,
        const float* __restrict__ kW, const float* __restrict__ kb, float* __restrict__ kacc,
        const float* __restrict__ lpW, const float* __restrict__ lpb,
        const float* __restrict__ poolw, float* __restrict__ macc,
        const int* __restrict__ csr, const int* __restrict__ pos,
        const float* __restrict__ als2, const float* __restrict__ ald2,
        const float* __restrict__ xh2, const float* __restrict__ bias,
        float* __restrict__ cur2T){
  __shared__ Smem sm;
  int t = threadIdx.x;
  if (blockIdx.x < 512){
    kde_phase(sm, cur1T, 0, 1, kW, kb, kacc, lpW, lpb, poolw, macc);  // already relu'd
  } else {
    int b2 = blockIdx.x - 512;
    int sub = t >> 7, tl = t & 127;
    int d = b2*4 + sub;
    float acc = gather_core(sm, d, sub, tl, csr, pos, als2, ald2, xh2, bias);
    sm.xw.rows[sub][tl] = acc;             // no relu on last layer
    __syncthreads();
    write_transposed(sm, t, b2*4, cur2T);
  }
}

// ================= L2: kde2(cur2T, coalesced) only =================
__global__ __launch_bounds__(512) void k_L2(const float* __restrict__ cur2T,
        const float* __restrict__ kW, const float* __restrict__ kb, float* __restrict__ kacc,
        const float* __restrict__ lpW, const float* __restrict__ lpb,
        const float* __restrict__ poolw, float* __restrict__ macc){
  __shared__ Smem sm;
  kde_phase(sm, cur2T, 0, 1, kW, kb, kacc, lpW, lpb, poolw, macc);
}

// ================= final: reduce 3 layers x 4 shards =================
__global__ void k_final(const float* __restrict__ maccS, const float* __restrict__ kaccS,
                        const float* __restrict__ beta, const float* __restrict__ h0,
                        float* __restrict__ out){
  int t = threadIdx.x;   // 128
  int g = t >> 5, o = t & 31;
  __shared__ float sdm[128];
  float s3 = 0.f;
  #pragma unroll
  for (int l=0;l<3;++l)
    #pragma unroll
    for (int s=0;s<4;++s)
      s3 += maccS[l*512 + s*128 + t] + kaccS[l*512 + s*128 + t];
  sdm[t] = s3 * (1.f/3.f) * beta[o];
  __syncthreads();
  if ((t & 31) == 0){
    float s = 0.f;
    #pragma unroll
    for (int i=0;i<32;++i) s += sdm[g*32+i];
    out[g] = s + h0[0];
  }
}

extern "C" void kernel_launch(void* const* d_in, const int* in_sizes, int n_in,
                              void* d_out, int out_size, void* d_ws, size_t ws_size,
                              hipStream_t stream) {
  (void)in_sizes; (void)n_in; (void)out_size; (void)ws_size;
  const float* x    = (const float*)d_in[0];
  const int*   ei   = (const int*)d_in[1];
  const int*   srcp = ei;
  const int*   dstp = ei + EE;
  const float* W[2]   = {(const float*)d_in[3], (const float*)d_in[7]};
  const float* As[2]  = {(const float*)d_in[4], (const float*)d_in[8]};
  const float* Ad[2]  = {(const float*)d_in[5], (const float*)d_in[9]};
  const float* Bi[2]  = {(const float*)d_in[6], (const float*)d_in[10]};
  const float* lpW[3] = {(const float*)d_in[11], (const float*)d_in[13], (const float*)d_in[15]};
  const float* lpb[3] = {(const float*)d_in[12], (const float*)d_in[14], (const float*)d_in[16]};
  const float* kW[3]  = {(const float*)d_in[17], (const float*)d_in[19], (const float*)d_in[21]};
  const float* kb[3]  = {(const float*)d_in[18], (const float*)d_in[20], (const float*)d_in[22]};
  const float* poolw  = (const float*)d_in[23];
  const float* beta   = (const float*)d_in[24];
  const float* h0     = (const float*)d_in[25];
  float* out = (float*)d_out;

  // workspace layout (floats unless noted)
  float* ws = (float*)d_ws;
  float* cur1T = ws;                   // 262144 (transposed [128][2048])
  float* cur2T = cur1T + 262144;       // 262144
  float* xh    = cur2T + 262144;       // 262144 (layer 0)
  float* xh2   = xh + 262144;          // 262144 (layer 1)
  float* als   = xh2 + 262144;         // 8192
  float* ald   = als + 8192;           // 8192
  float* als2  = ald + 8192;           // 8192
  float* ald2  = als2 + 8192;          // 8192
  float* maccS = ald2 + 8192;          // 1536 (3 layers x 4 shards x 128)
  float* kaccS = maccS + 1536;         // 1536
  int*   pos   = (int*)(kaccS + 1536); // 2048
  int*   csr   = pos + 2048;           // 2048*160

  k_zero<<<1, 1024, 0, stream>>>(pos, maccS);
  k_L0<<<1024, 512, 0, stream>>>(x, kW[0], kb[0], kaccS, lpW[0], lpb[0], poolw, maccS,
                                 W[0], As[0], Ad[0], xh, als, ald,
                                 srcp, dstp, pos, csr);
  k_G0<<<512, 512, 0, stream>>>(csr, pos, als, ald, xh, Bi[0], cur1T,
                                W[1], As[1], Ad[1], xh2, als2, ald2);
  k_L1<<<1024, 512, 0, stream>>>(cur1T, kW[1], kb[1], kaccS+512, lpW[1], lpb[1], poolw, maccS+512,
                                 csr, pos, als2, ald2, xh2, Bi[1], cur2T);
  k_L2<<<512, 512, 0, stream>>>(cur2T, kW[2], kb[2], kaccS+1024, lpW[2], lpb[2], poolw, maccS+1024);
  k_final<<<1, 128, 0, stream>>>(maccS, kaccS, beta, h0, out);
}